// Round 1
// baseline (2014.342 us; speedup 1.0000x reference)
//
#include <hip/hip_runtime.h>

#define B_GRAPHS 8192
#define NN 54
#define NE 144
#define FN 18
#define FE 5
#define HD 48
#define NOUT 80
#define NL 3
#define HP 52   // padded row stride for [.][48] LDS tiles (multiple of 4, breaks pow2 banks)

__device__ __forceinline__ float mish_f(float x) {
  // mish(x) = x * tanh(softplus(x)) = x * (s^2-1)/(s^2+1), s = 1+e^x
  float t = __expf(x);
  float s = 1.0f + t;
  float s2 = s * s;
  float r = (s2 - 1.0f) * __builtin_amdgcn_rcpf(s2 + 1.0f);
  return (x > 20.0f) ? x : x * r;
}

// ---------------- setup: folded edge weights + incoming-edge CSR ----------------
__global__ void gnn_setup(const float* __restrict__ w_edge,
                          const float* __restrict__ b_edge,
                          const float* __restrict__ msg_w1,
                          const int*  __restrict__ edge_index,
                          float* __restrict__ wsf, int* __restrict__ wsi) {
  int t = threadIdx.x;
  // W_eff[l][j][c] = sum_k w_edge[j][k] * msg_w1[l][2H+k][c]
  for (int idx = t; idx < NL * FE * HD; idx += 256) {
    int l = idx / (FE * HD);
    int r = idx % (FE * HD);
    int j = r / HD, c = r % HD;
    float s = 0.f;
    for (int k = 0; k < HD; ++k)
      s += w_edge[j * HD + k] * msg_w1[((l * 3 * HD) + 2 * HD + k) * HD + c];
    wsf[idx] = s;
  }
  // b_eff[l][c] = sum_k b_edge[k] * msg_w1[l][2H+k][c]
  for (int idx = t; idx < NL * HD; idx += 256) {
    int l = idx / HD, c = idx % HD;
    float s = 0.f;
    for (int k = 0; k < HD; ++k)
      s += b_edge[k] * msg_w1[((l * 3 * HD) + 2 * HD + k) * HD + c];
    wsf[NL * FE * HD + idx] = s;
  }
  // CSR of incoming edges per node (same topology for all graphs)
  __shared__ int deg[NN];
  const int* dst = edge_index + NE;
  if (t < NN) {
    int c = 0;
    for (int e = 0; e < NE; ++e) c += (dst[e] == t) ? 1 : 0;
    deg[t] = c;
  }
  __syncthreads();
  if (t == 0) {
    int run = 0;
    for (int n = 0; n < NN; ++n) { wsi[n] = run; run += deg[n]; }
    wsi[NN] = run;
  }
  __syncthreads();
  if (t < NN) {
    int p = wsi[t];
    for (int e = 0; e < NE; ++e)
      if (dst[e] == t) wsi[NN + 1 + (p++)] = e;
  }
}

// ---------------- main: one block per graph ----------------
__global__ __launch_bounds__(256) void gnn_main(
    const float* __restrict__ nf, const float* __restrict__ efx,
    const float* __restrict__ w_node, const float* __restrict__ b_node,
    const float* __restrict__ msg_w1, const float* __restrict__ msg_b1,
    const float* __restrict__ msg_w2, const float* __restrict__ msg_b2,
    const float* __restrict__ upd_w1, const float* __restrict__ upd_b1,
    const float* __restrict__ upd_w2, const float* __restrict__ upd_b2,
    const float* __restrict__ ln_g, const float* __restrict__ ln_b,
    const float* __restrict__ w_out1, const float* __restrict__ b_out1,
    const float* __restrict__ w_out2, const float* __restrict__ b_out2,
    const int* __restrict__ edge_index,
    const float* __restrict__ wsf, const int* __restrict__ wsi,
    float* __restrict__ out)
{
  __shared__ __align__(16) float h_s[NN][HP];
  __shared__ __align__(16) float m_s[NE][HP];
  __shared__ __align__(16) float agg_s[NN][HP];
  __shared__ float ef_s[NE][6];
  __shared__ float weff_s[NL * FE * HD];
  __shared__ float beff_s[NL * HD];
  __shared__ int   src_s[NE], dst_s[NE];
  __shared__ int   off_s[NN + 1];
  __shared__ int   list_s[NE];
  __shared__ float mu_s[NN], rs_s[NN];
  __shared__ float pool_s[2 * HD];
  __shared__ float o1_s[NOUT];

  const int b = blockIdx.x;
  const int t = threadIdx.x;
  const int tx = t & 15, ty = t >> 4;

  // ---- phase 0: stage small shared data ----
  if (t < NE) { src_s[t] = edge_index[t]; dst_s[t] = edge_index[NE + t]; }
  if (t < NN + 1) off_s[t] = wsi[t];
  if (t < NE) list_s[t] = wsi[NN + 1 + t];
  for (int idx = t; idx < NL * FE * HD; idx += 256) weff_s[idx] = wsf[idx];
  if (t < NL * HD) beff_s[t] = wsf[NL * FE * HD + t];
  for (int idx = t; idx < NE * FE; idx += 256)
    ef_s[idx / FE][idx % FE] = efx[(size_t)b * NE * FE + idx];
  __syncthreads();

  // ---- phase 1: h = mish(nf @ w_node + b_node) ----
  {
    const float* nfb = nf + (size_t)b * NN * FN;
    #pragma unroll
    for (int i = 0; i < 4; ++i) {
      int n = ty + 16 * i;
      if (n < NN) {
        float a0 = b_node[tx], a1 = b_node[tx + 16], a2 = b_node[tx + 32];
        #pragma unroll
        for (int k = 0; k < FN; ++k) {
          float v = nfb[n * FN + k];
          const float* wr = w_node + k * HD;
          a0 += v * wr[tx]; a1 += v * wr[tx + 16]; a2 += v * wr[tx + 32];
        }
        h_s[n][tx] = mish_f(a0);
        h_s[n][tx + 16] = mish_f(a1);
        h_s[n][tx + 32] = mish_f(a2);
      }
    }
  }
  __syncthreads();

  int se[9], de[9];
  #pragma unroll
  for (int i = 0; i < 9; ++i) { se[i] = src_s[ty + 16 * i]; de[i] = dst_s[ty + 16 * i]; }

  for (int l = 0; l < NL; ++l) {
    const int l48 = l * HD;
    const float* w1 = msg_w1 + l * (3 * HD * HD);

    // ---- msg1: m = mish([h[src], h[dst], e] @ msg_w1 + b1) ----
    {
      float acc[9][3];
      float bb[3];
      #pragma unroll
      for (int j = 0; j < 3; ++j)
        bb[j] = msg_b1[l48 + tx + 16 * j] + beff_s[l48 + tx + 16 * j];
      #pragma unroll
      for (int i = 0; i < 9; ++i)
        #pragma unroll
        for (int j = 0; j < 3; ++j) acc[i][j] = bb[j];
      // folded edge-feature part
      #pragma unroll
      for (int q = 0; q < FE; ++q) {
        float wq[3];
        #pragma unroll
        for (int j = 0; j < 3; ++j) wq[j] = weff_s[(l * FE + q) * HD + tx + 16 * j];
        #pragma unroll
        for (int i = 0; i < 9; ++i) {
          float ev = ef_s[ty + 16 * i][q];
          #pragma unroll
          for (int j = 0; j < 3; ++j) acc[i][j] += ev * wq[j];
        }
      }
      // src part: rows [0,48)
      for (int kq = 0; kq < 12; ++kq) {
        float w[4][3];
        #pragma unroll
        for (int dk = 0; dk < 4; ++dk)
          #pragma unroll
          for (int j = 0; j < 3; ++j)
            w[dk][j] = w1[(kq * 4 + dk) * HD + tx + 16 * j];
        #pragma unroll
        for (int i = 0; i < 9; ++i) {
          float4 hv = *(const float4*)&h_s[se[i]][kq * 4];
          #pragma unroll
          for (int j = 0; j < 3; ++j)
            acc[i][j] += hv.x * w[0][j] + hv.y * w[1][j] + hv.z * w[2][j] + hv.w * w[3][j];
        }
      }
      // dst part: rows [48,96)
      for (int kq = 0; kq < 12; ++kq) {
        float w[4][3];
        #pragma unroll
        for (int dk = 0; dk < 4; ++dk)
          #pragma unroll
          for (int j = 0; j < 3; ++j)
            w[dk][j] = w1[(HD + kq * 4 + dk) * HD + tx + 16 * j];
        #pragma unroll
        for (int i = 0; i < 9; ++i) {
          float4 hv = *(const float4*)&h_s[de[i]][kq * 4];
          #pragma unroll
          for (int j = 0; j < 3; ++j)
            acc[i][j] += hv.x * w[0][j] + hv.y * w[1][j] + hv.z * w[2][j] + hv.w * w[3][j];
        }
      }
      #pragma unroll
      for (int i = 0; i < 9; ++i)
        #pragma unroll
        for (int j = 0; j < 3; ++j)
          m_s[ty + 16 * i][tx + 16 * j] = mish_f(acc[i][j]);
    }
    __syncthreads();

    // ---- msg2: m = mish(m @ msg_w2 + b2), in place ----
    {
      const float* w2 = msg_w2 + l * (HD * HD);
      float a2[9][3];
      float bb[3];
      #pragma unroll
      for (int j = 0; j < 3; ++j) bb[j] = msg_b2[l48 + tx + 16 * j];
      #pragma unroll
      for (int i = 0; i < 9; ++i)
        #pragma unroll
        for (int j = 0; j < 3; ++j) a2[i][j] = bb[j];
      for (int kq = 0; kq < 12; ++kq) {
        float w[4][3];
        #pragma unroll
        for (int dk = 0; dk < 4; ++dk)
          #pragma unroll
          for (int j = 0; j < 3; ++j)
            w[dk][j] = w2[(kq * 4 + dk) * HD + tx + 16 * j];
        #pragma unroll
        for (int i = 0; i < 9; ++i) {
          float4 mv = *(const float4*)&m_s[ty + 16 * i][kq * 4];
          #pragma unroll
          for (int j = 0; j < 3; ++j)
            a2[i][j] += mv.x * w[0][j] + mv.y * w[1][j] + mv.z * w[2][j] + mv.w * w[3][j];
        }
      }
      #pragma unroll
      for (int i = 0; i < 9; ++i)
        #pragma unroll
        for (int j = 0; j < 3; ++j) a2[i][j] = mish_f(a2[i][j]);
      __syncthreads();  // all reads of m1 done
      #pragma unroll
      for (int i = 0; i < 9; ++i)
        #pragma unroll
        for (int j = 0; j < 3; ++j)
          m_s[ty + 16 * i][tx + 16 * j] = a2[i][j];
    }
    __syncthreads();

    // ---- agg: segment-sum of messages at dst (CSR, deterministic) ----
    #pragma unroll
    for (int i = 0; i < 4; ++i) {
      int n = ty + 16 * i;
      if (n < NN) {
        float s0 = 0.f, s1 = 0.f, s2v = 0.f;
        int p0 = off_s[n], p1 = off_s[n + 1];
        for (int p = p0; p < p1; ++p) {
          int e = list_s[p];
          s0 += m_s[e][tx]; s1 += m_s[e][tx + 16]; s2v += m_s[e][tx + 32];
        }
        agg_s[n][tx] = s0; agg_s[n][tx + 16] = s1; agg_s[n][tx + 32] = s2v;
      }
    }
    __syncthreads();

    // ---- upd1: u = mish([h, agg] @ upd_w1 + b1) -> m_s rows [0,54) ----
    {
      const float* wu = upd_w1 + l * (2 * HD * HD);
      float au[4][3];
      float bb[3];
      #pragma unroll
      for (int j = 0; j < 3; ++j) bb[j] = upd_b1[l48 + tx + 16 * j];
      #pragma unroll
      for (int i = 0; i < 4; ++i)
        #pragma unroll
        for (int j = 0; j < 3; ++j) au[i][j] = bb[j];
      for (int kq = 0; kq < 12; ++kq) {
        float w[4][3];
        #pragma unroll
        for (int dk = 0; dk < 4; ++dk)
          #pragma unroll
          for (int j = 0; j < 3; ++j)
            w[dk][j] = wu[(kq * 4 + dk) * HD + tx + 16 * j];
        #pragma unroll
        for (int i = 0; i < 4; ++i) {
          int n = ty + 16 * i;
          if (n < NN) {
            float4 hv = *(const float4*)&h_s[n][kq * 4];
            #pragma unroll
            for (int j = 0; j < 3; ++j)
              au[i][j] += hv.x * w[0][j] + hv.y * w[1][j] + hv.z * w[2][j] + hv.w * w[3][j];
          }
        }
      }
      for (int kq = 0; kq < 12; ++kq) {
        float w[4][3];
        #pragma unroll
        for (int dk = 0; dk < 4; ++dk)
          #pragma unroll
          for (int j = 0; j < 3; ++j)
            w[dk][j] = wu[(HD + kq * 4 + dk) * HD + tx + 16 * j];
        #pragma unroll
        for (int i = 0; i < 4; ++i) {
          int n = ty + 16 * i;
          if (n < NN) {
            float4 av = *(const float4*)&agg_s[n][kq * 4];
            #pragma unroll
            for (int j = 0; j < 3; ++j)
              au[i][j] += av.x * w[0][j] + av.y * w[1][j] + av.z * w[2][j] + av.w * w[3][j];
          }
        }
      }
      #pragma unroll
      for (int i = 0; i < 4; ++i) {
        int n = ty + 16 * i;
        if (n < NN) {
          #pragma unroll
          for (int j = 0; j < 3; ++j)
            m_s[n][tx + 16 * j] = mish_f(au[i][j]);
        }
      }
    }
    __syncthreads();

    // ---- upd2 + residual: x = h + (u @ upd_w2 + b2) -> agg_s ----
    {
      const float* wu = upd_w2 + l * (HD * HD);
      float ax[4][3];
      float bb[3];
      #pragma unroll
      for (int j = 0; j < 3; ++j) bb[j] = upd_b2[l48 + tx + 16 * j];
      #pragma unroll
      for (int i = 0; i < 4; ++i)
        #pragma unroll
        for (int j = 0; j < 3; ++j) ax[i][j] = bb[j];
      for (int kq = 0; kq < 12; ++kq) {
        float w[4][3];
        #pragma unroll
        for (int dk = 0; dk < 4; ++dk)
          #pragma unroll
          for (int j = 0; j < 3; ++j)
            w[dk][j] = wu[(kq * 4 + dk) * HD + tx + 16 * j];
        #pragma unroll
        for (int i = 0; i < 4; ++i) {
          int n = ty + 16 * i;
          if (n < NN) {
            float4 mv = *(const float4*)&m_s[n][kq * 4];
            #pragma unroll
            for (int j = 0; j < 3; ++j)
              ax[i][j] += mv.x * w[0][j] + mv.y * w[1][j] + mv.z * w[2][j] + mv.w * w[3][j];
          }
        }
      }
      #pragma unroll
      for (int i = 0; i < 4; ++i) {
        int n = ty + 16 * i;
        if (n < NN) {
          #pragma unroll
          for (int j = 0; j < 3; ++j) {
            int c = tx + 16 * j;
            agg_s[n][c] = h_s[n][c] + ax[i][j];
          }
        }
      }
    }
    __syncthreads();

    // ---- LayerNorm over channels -> h_s ----
    if (t < NN) {
      float s = 0.f, q = 0.f;
      #pragma unroll
      for (int k = 0; k < HD; ++k) { float v = agg_s[t][k]; s += v; q += v * v; }
      float mu = s * (1.0f / HD);
      float var = q * (1.0f / HD) - mu * mu;
      mu_s[t] = mu;
      rs_s[t] = rsqrtf(var + 1e-5f);
    }
    __syncthreads();
    #pragma unroll
    for (int i = 0; i < 4; ++i) {
      int n = ty + 16 * i;
      if (n < NN) {
        float mu = mu_s[n], rs = rs_s[n];
        #pragma unroll
        for (int j = 0; j < 3; ++j) {
          int c = tx + 16 * j;
          float x = agg_s[n][c];
          h_s[n][c] = (x - mu) * rs * ln_g[l48 + c] + ln_b[l48 + c];
        }
      }
    }
    __syncthreads();
  }

  // ---- write node embeddings ----
  {
    float* noder = out + (size_t)B_GRAPHS * NOUT + (size_t)b * (NN * HD);
    for (int idx = t; idx < NN * HD; idx += 256)
      noder[idx] = h_s[idx / HD][idx % HD];
  }

  // ---- pooling ----
  if (t < HD) {
    float sm = 0.f, mx = -3.0e38f;
    for (int n = 0; n < NN; ++n) { float v = h_s[n][t]; sm += v; mx = fmaxf(mx, v); }
    pool_s[t] = sm * (1.0f / NN);
    pool_s[HD + t] = mx;
  }
  __syncthreads();

  // ---- output MLP ----
  if (t < NOUT) {
    float a = b_out1[t];
    #pragma unroll
    for (int k = 0; k < 2 * HD; ++k) a += pool_s[k] * w_out1[k * NOUT + t];
    o1_s[t] = mish_f(a);
  }
  __syncthreads();
  if (t < NOUT) {
    float a = b_out2[t];
    #pragma unroll
    for (int k = 0; k < NOUT; ++k) a += o1_s[k] * w_out2[k * NOUT + t];
    out[(size_t)b * NOUT + t] = a;
  }
}

extern "C" void kernel_launch(void* const* d_in, const int* in_sizes, int n_in,
                              void* d_out, int out_size, void* d_ws, size_t ws_size,
                              hipStream_t stream) {
  const float* nf     = (const float*)d_in[0];
  const float* ef     = (const float*)d_in[1];
  const float* w_node = (const float*)d_in[2];
  const float* b_node = (const float*)d_in[3];
  const float* w_edge = (const float*)d_in[4];
  const float* b_edge = (const float*)d_in[5];
  const float* msg_w1 = (const float*)d_in[6];
  const float* msg_b1 = (const float*)d_in[7];
  const float* msg_w2 = (const float*)d_in[8];
  const float* msg_b2 = (const float*)d_in[9];
  const float* upd_w1 = (const float*)d_in[10];
  const float* upd_b1 = (const float*)d_in[11];
  const float* upd_w2 = (const float*)d_in[12];
  const float* upd_b2 = (const float*)d_in[13];
  const float* ln_g   = (const float*)d_in[14];
  const float* ln_b   = (const float*)d_in[15];
  const float* w_out1 = (const float*)d_in[16];
  const float* b_out1 = (const float*)d_in[17];
  const float* w_out2 = (const float*)d_in[18];
  const float* b_out2 = (const float*)d_in[19];
  const int* edge_index = (const int*)d_in[20];

  float* wsf = (float*)d_ws;
  int*   wsi = (int*)d_ws + 2048;  // byte offset 8192

  gnn_setup<<<1, 256, 0, stream>>>(w_edge, b_edge, msg_w1, edge_index, wsf, wsi);
  gnn_main<<<B_GRAPHS, 256, 0, stream>>>(nf, ef, w_node, b_node, msg_w1, msg_b1,
      msg_w2, msg_b2, upd_w1, upd_b1, upd_w2, upd_b2, ln_g, ln_b,
      w_out1, b_out1, w_out2, b_out2, edge_index, wsf, wsi, (float*)d_out);
}

// Round 2
// 483.126 us; speedup vs baseline: 4.1694x; 4.1694x over previous
//
#include <hip/hip_runtime.h>

#define NGR 8192
#define NN 54
#define NE 144
#define FN 18
#define FE 5
#define HD 48
#define NOUT 80
#define NL 3
#define HS 56   // h/agg LDS row stride (bf16 elems): 112B, 2-way banks max
#define MS 72   // m LDS row stride: 144B
#define ES 40   // ef LDS row stride: 80B
#define NFRAG (3 + NL * 33)

typedef short v8s __attribute__((ext_vector_type(8)));
typedef short v4s __attribute__((ext_vector_type(4)));
typedef float v4f __attribute__((ext_vector_type(4)));

#define MFMA(a, bf, c) __builtin_amdgcn_mfma_f32_16x16x32_bf16((a), (bf), (c), 0, 0, 0)

static __device__ __forceinline__ float mish_f(float x) {
  float t = __expf(x);
  float s = 1.0f + t;
  float s2 = s * s;
  float r = (s2 - 1.0f) * __builtin_amdgcn_rcpf(s2 + 1.0f);
  return (x > 20.0f) ? x : x * r;
}
static __device__ __forceinline__ short f2b(float x) {  // fp32 -> bf16 (RNE)
  union { float f; unsigned u; } v; v.f = x;
  unsigned r = v.u + 0x7FFFu + ((v.u >> 16) & 1u);
  return (short)(r >> 16);
}
static __device__ __forceinline__ float b2f(short s) {
  union { unsigned u; float f; } v; v.u = ((unsigned)(unsigned short)s) << 16;
  return v.f;
}

// ---------------- setup: CSR + folded bias + MFMA B-fragment prepack ----------------
__global__ void gnn_setup(const float* __restrict__ w_node,
                          const float* __restrict__ w_edge,
                          const float* __restrict__ b_edge,
                          const float* __restrict__ msg_w1,
                          const float* __restrict__ msg_b1,
                          const float* __restrict__ msg_w2,
                          const float* __restrict__ upd_w1,
                          const float* __restrict__ upd_w2,
                          const int* __restrict__ edge_index,
                          int* __restrict__ wsi, float* __restrict__ mb1,
                          short* __restrict__ frags) {
  const int t = threadIdx.x;
  if (blockIdx.x == 0) {
    __shared__ int deg[NN];
    const int* dst = edge_index + NE;
    if (t < NN) {
      int c = 0;
      for (int e = 0; e < NE; ++e) c += (dst[e] == t) ? 1 : 0;
      deg[t] = c;
    }
    __syncthreads();
    if (t == 0) {
      int run = 0;
      for (int n = 0; n < NN; ++n) { wsi[n] = run; run += deg[n]; }
      wsi[NN] = run;
    }
    __syncthreads();
    if (t < NN) {
      int p = wsi[t];
      for (int e = 0; e < NE; ++e)
        if (dst[e] == t) wsi[NN + 1 + (p++)] = e;
    }
    // mb1[l][c] = msg_b1[l][c] + b_edge @ msg_w1[l][96:144]
    for (int idx = t; idx < NL * HD; idx += 256) {
      int l = idx / HD, c = idx % HD;
      float s = msg_b1[l * HD + c];
      for (int k = 0; k < HD; ++k)
        s += b_edge[k] * msg_w1[(l * 144 + 96 + k) * HD + c];
      mb1[idx] = s;
    }
  }
  // B-fragments: frag f, lane l, elem j holds W[ks*32 + (l>>4)*8 + j][nt*16 + (l&15)]
  for (int eid = blockIdx.x * 256 + t; eid < NFRAG * 512; eid += gridDim.x * 256) {
    int f = eid >> 9, r = eid & 511;
    int lane = r >> 3, j = r & 7;
    int kk = ((lane >> 4) << 3) + j;
    int colq = lane & 15;
    float val = 0.f;
    if (f < 3) {                       // w_node (K=18 pad 32), nt=f
      int c = f * 16 + colq;
      if (kk < FN) val = w_node[kk * HD + c];
    } else {
      int g = f - 3, l = g / 33, o = g % 33;
      if (o < 9) {                     // msg_w1 rows 0..95: ks=o/3, nt=o%3
        int ks = o / 3, nt = o % 3, c = nt * 16 + colq, k = ks * 32 + kk;
        val = msg_w1[(l * 144 + k) * HD + c];
      } else if (o < 12) {             // W_eff = w_edge @ msg_w1[96:144] (K=5 pad 32)
        int nt = o - 9, c = nt * 16 + colq;
        if (kk < FE) {
          float s = 0.f;
          for (int k2 = 0; k2 < HD; ++k2)
            s += w_edge[kk * HD + k2] * msg_w1[(l * 144 + 96 + k2) * HD + c];
          val = s;
        }
      } else if (o < 18) {             // msg_w2 (K=48 pad 64)
        int oo = o - 12, ks = oo / 3, nt = oo % 3, c = nt * 16 + colq, k = ks * 32 + kk;
        if (k < HD) val = msg_w2[(l * HD + k) * HD + c];
      } else if (o < 27) {             // upd_w1 (K=96)
        int oo = o - 18, ks = oo / 3, nt = oo % 3, c = nt * 16 + colq, k = ks * 32 + kk;
        val = upd_w1[(l * 96 + k) * HD + c];
      } else {                         // upd_w2 (K=48 pad 64)
        int oo = o - 27, ks = oo / 3, nt = oo % 3, c = nt * 16 + colq, k = ks * 32 + kk;
        if (k < HD) val = upd_w2[(l * HD + k) * HD + c];
      }
    }
    frags[eid] = f2b(val);
  }
}

// ---------------- main: one block (4 waves) per graph ----------------
__global__ __launch_bounds__(256, 3) void gnn_main(
    const float* __restrict__ nf, const float* __restrict__ efx,
    const float* __restrict__ b_node,
    const float* __restrict__ msg_b2,
    const float* __restrict__ upd_b1, const float* __restrict__ upd_b2,
    const float* __restrict__ ln_g, const float* __restrict__ ln_b,
    const float* __restrict__ w_out1, const float* __restrict__ b_out1,
    const float* __restrict__ w_out2, const float* __restrict__ b_out2,
    const int* __restrict__ edge_index,
    const int* __restrict__ wsi, const float* __restrict__ mb1,
    const short* __restrict__ frags,
    float* __restrict__ out)
{
  __shared__ __align__(16) short h_s[64][HS];
  __shared__ __align__(16) short agg_s[64][HS];
  __shared__ __align__(16) short m_s[NE][MS];
  __shared__ __align__(16) short ef_s[NE][ES];
  __shared__ int src_s[NE], dst_s[NE], off_s[NN + 1], list_s[NE];
  __shared__ float pool_s[2 * HD];
  __shared__ float o1_s[NOUT];

  const int b = blockIdx.x;
  const int t = threadIdx.x;
  const int lane = t & 63;
  const int w = t >> 6;            // wave id 0..3
  const int lx = lane & 15;        // A-row / C-col within tile
  const int lg = (lane >> 4) & 3;  // k-group / C-row-group
  const int koff = lg << 3;

  // ---- stage + zero-init ----
  if (t < NE) { src_s[t] = edge_index[t] * HS; dst_s[t] = edge_index[NE + t] * HS; }
  if (t < NN + 1) off_s[t] = wsi[t];
  if (t < NE) list_s[t] = wsi[NN + 1 + t];
  for (int idx = t; idx < NE * ES; idx += 256) {
    int r = idx / ES, c = idx % ES;
    ef_s[r][c] = (c < FE) ? f2b(efx[(size_t)b * (NE * FE) + r * FE + c]) : (short)0;
  }
  for (int idx = t; idx < 64 * 32; idx += 256) {   // nf into agg (K=18 pad 32), rows 54-63 zero
    int r = idx >> 5, c = idx & 31;
    agg_s[r][c] = (r < NN && c < FN) ? f2b(nf[(size_t)b * (NN * FN) + r * FN + c]) : (short)0;
  }
  for (int idx = t; idx < 10 * 16; idx += 256)
    agg_s[54 + (idx >> 4)][32 + (idx & 15)] = 0;   // agg pad rows, cols 32-47
  for (int idx = t; idx < 10 * 48; idx += 256)
    h_s[54 + idx / 48][idx % 48] = 0;              // h pad rows
  for (int idx = t; idx < NE * 16; idx += 256)
    m_s[idx >> 4][48 + (idx & 15)] = 0;            // m K-pad cols 48-63 (never rewritten)
  __syncthreads();

  const short* h0 = &h_s[0][0];
  const short* g0 = &agg_s[0][0];
  const short* m0 = &m_s[0][0];

  // ---- input proj: h = mish(nf @ w_node + b_node), wave w -> rows w*16.. ----
  {
    v8s bw[3];
    #pragma unroll
    for (int nt = 0; nt < 3; ++nt)
      bw[nt] = *(const v8s*)(frags + (size_t)nt * 512 + lane * 8);
    v8s a = *(const v8s*)(g0 + (w * 16 + lx) * HS + koff);
    v4f acc[3];
    #pragma unroll
    for (int nt = 0; nt < 3; ++nt) {
      float bb = b_node[nt * 16 + lx];
      acc[nt] = (v4f){bb, bb, bb, bb};
      acc[nt] = MFMA(a, bw[nt], acc[nt]);
    }
    int orow = w * 16 + lg * 4;
    #pragma unroll
    for (int nt = 0; nt < 3; ++nt)
      #pragma unroll
      for (int r = 0; r < 4; ++r)
        if (orow + r < NN) h_s[orow + r][nt * 16 + lx] = f2b(mish_f(acc[nt][r]));
  }
  __syncthreads();

  for (int l = 0; l < NL; ++l) {
    const short* FB = frags + (size_t)(3 + l * 33) * 512;
    v8s bw1[3][3], bwe[3], bw2[2][3];
    float bm1[3], bm2[3];
    #pragma unroll
    for (int ks = 0; ks < 3; ++ks)
      #pragma unroll
      for (int nt = 0; nt < 3; ++nt)
        bw1[ks][nt] = *(const v8s*)(FB + (size_t)(ks * 3 + nt) * 512 + lane * 8);
    #pragma unroll
    for (int nt = 0; nt < 3; ++nt)
      bwe[nt] = *(const v8s*)(FB + (size_t)(9 + nt) * 512 + lane * 8);
    #pragma unroll
    for (int ks = 0; ks < 2; ++ks)
      #pragma unroll
      for (int nt = 0; nt < 3; ++nt)
        bw2[ks][nt] = *(const v8s*)(FB + (size_t)(12 + ks * 3 + nt) * 512 + lane * 8);
    #pragma unroll
    for (int nt = 0; nt < 3; ++nt) {
      bm1[nt] = mb1[l * HD + nt * 16 + lx];
      bm2[nt] = msg_b2[(size_t)l * HD + nt * 16 + lx];
    }

    // ---- msg1 + msg2 fused per M-tile (wave-exclusive rows; in-order LDS) ----
    for (int mt = w; mt < 9; mt += 4) {
      int e_ = mt * 16 + lx;
      int rs = src_s[e_], rd = dst_s[e_];
      int orow = mt * 16 + lg * 4;
      v4f acc[3];
      // msg1: e-part (K=32 pad) then h[src]|h[dst] (K=96)
      v8s ae = *(const v8s*)(&ef_s[0][0] + e_ * ES + koff);
      #pragma unroll
      for (int nt = 0; nt < 3; ++nt) {
        acc[nt] = (v4f){bm1[nt], bm1[nt], bm1[nt], bm1[nt]};
        acc[nt] = MFMA(ae, bwe[nt], acc[nt]);
      }
      #pragma unroll
      for (int ks = 0; ks < 3; ++ks) {
        int kk = ks * 32 + koff;
        const short* ap = (kk < 48) ? (h0 + rs + kk) : (h0 + rd + kk - 48);
        v8s a = *(const v8s*)ap;
        #pragma unroll
        for (int nt = 0; nt < 3; ++nt) acc[nt] = MFMA(a, bw1[ks][nt], acc[nt]);
      }
      #pragma unroll
      for (int nt = 0; nt < 3; ++nt)
        #pragma unroll
        for (int r = 0; r < 4; ++r)
          m_s[orow + r][nt * 16 + lx] = f2b(mish_f(acc[nt][r]));
      // msg2 (reads rows this wave just wrote; same-wave LDS is in-order)
      const short* mrow = m0 + (mt * 16 + lx) * MS;
      v8s a0 = *(const v8s*)(mrow + koff);
      v8s a1 = *(const v8s*)(mrow + 32 + koff);
      #pragma unroll
      for (int nt = 0; nt < 3; ++nt) {
        acc[nt] = (v4f){bm2[nt], bm2[nt], bm2[nt], bm2[nt]};
        acc[nt] = MFMA(a0, bw2[0][nt], acc[nt]);
        acc[nt] = MFMA(a1, bw2[1][nt], acc[nt]);
      }
      #pragma unroll
      for (int nt = 0; nt < 3; ++nt)
        #pragma unroll
        for (int r = 0; r < 4; ++r)
          m_s[orow + r][nt * 16 + lx] = f2b(mish_f(acc[nt][r]));
    }
    __syncthreads();

    // ---- agg: CSR segment-sum (bf16 in, fp32 accum, bf16 out) ----
    for (int task = t; task < NN * 12; task += 256) {
      int n = task / 12, q = (task % 12) * 4;
      float s0 = 0.f, s1 = 0.f, s2 = 0.f, s3 = 0.f;
      int p1 = off_s[n + 1];
      for (int p = off_s[n]; p < p1; ++p) {
        v4s v = *(const v4s*)(m0 + list_s[p] * MS + q);
        s0 += b2f(v[0]); s1 += b2f(v[1]); s2 += b2f(v[2]); s3 += b2f(v[3]);
      }
      v4s o; o[0] = f2b(s0); o[1] = f2b(s1); o[2] = f2b(s2); o[3] = f2b(s3);
      *(v4s*)(&agg_s[0][0] + n * HS + q) = o;
    }
    __syncthreads();

    // ---- upd1 + upd2 + residual + LN (wave w owns node rows w*16..) ----
    {
      v8s u1[3][3], u2[2][3];
      float bu1[3], bu2[3], lg_[3], lb_[3];
      #pragma unroll
      for (int ks = 0; ks < 3; ++ks)
        #pragma unroll
        for (int nt = 0; nt < 3; ++nt)
          u1[ks][nt] = *(const v8s*)(FB + (size_t)(18 + ks * 3 + nt) * 512 + lane * 8);
      #pragma unroll
      for (int ks = 0; ks < 2; ++ks)
        #pragma unroll
        for (int nt = 0; nt < 3; ++nt)
          u2[ks][nt] = *(const v8s*)(FB + (size_t)(27 + ks * 3 + nt) * 512 + lane * 8);
      #pragma unroll
      for (int nt = 0; nt < 3; ++nt) {
        bu1[nt] = upd_b1[(size_t)l * HD + nt * 16 + lx];
        bu2[nt] = upd_b2[(size_t)l * HD + nt * 16 + lx];
        lg_[nt] = ln_g[(size_t)l * HD + nt * 16 + lx];
        lb_[nt] = ln_b[(size_t)l * HD + nt * 16 + lx];
      }
      const int nrow = w * 16 + lx;
      const int orow = w * 16 + lg * 4;
      v4f acc[3];
      #pragma unroll
      for (int nt = 0; nt < 3; ++nt) acc[nt] = (v4f){bu1[nt], bu1[nt], bu1[nt], bu1[nt]};
      #pragma unroll
      for (int ks = 0; ks < 3; ++ks) {
        int kk = ks * 32 + koff;
        const short* ap = (kk < 48) ? (h0 + nrow * HS + kk) : (g0 + nrow * HS + kk - 48);
        v8s a = *(const v8s*)ap;
        #pragma unroll
        for (int nt = 0; nt < 3; ++nt) acc[nt] = MFMA(a, u1[ks][nt], acc[nt]);
      }
      #pragma unroll
      for (int nt = 0; nt < 3; ++nt)
        #pragma unroll
        for (int r = 0; r < 4; ++r)
          m_s[orow + r][nt * 16 + lx] = f2b(mish_f(acc[nt][r]));
      // upd2 (same-wave rows, in-order)
      const short* mrow = m0 + nrow * MS;
      v8s a0 = *(const v8s*)(mrow + koff);
      v8s a1 = *(const v8s*)(mrow + 32 + koff);
      #pragma unroll
      for (int nt = 0; nt < 3; ++nt) {
        acc[nt] = (v4f){bu2[nt], bu2[nt], bu2[nt], bu2[nt]};
        acc[nt] = MFMA(a0, u2[0][nt], acc[nt]);
        acc[nt] = MFMA(a1, u2[1][nt], acc[nt]);
      }
      // residual + LN (row stats via shfl over the 16 lanes holding the row)
      float x[3][4], s[4], q[4];
      #pragma unroll
      for (int r = 0; r < 4; ++r) {
        #pragma unroll
        for (int nt = 0; nt < 3; ++nt)
          x[nt][r] = acc[nt][r] + b2f(h_s[orow + r][nt * 16 + lx]);
        s[r] = x[0][r] + x[1][r] + x[2][r];
        q[r] = x[0][r] * x[0][r] + x[1][r] * x[1][r] + x[2][r] * x[2][r];
      }
      #pragma unroll
      for (int mask = 1; mask <= 8; mask <<= 1)
        #pragma unroll
        for (int r = 0; r < 4; ++r) {
          s[r] += __shfl_xor(s[r], mask);
          q[r] += __shfl_xor(q[r], mask);
        }
      float* onode = out + (size_t)NGR * NOUT + (size_t)b * (NN * HD);
      #pragma unroll
      for (int r = 0; r < 4; ++r) {
        float mu = s[r] * (1.0f / HD);
        float vr = q[r] * (1.0f / HD) - mu * mu;
        float rsg = rsqrtf(vr + 1e-5f);
        int row = orow + r;
        #pragma unroll
        for (int nt = 0; nt < 3; ++nt) {
          float y = (x[nt][r] - mu) * rsg * lg_[nt] + lb_[nt];
          if (row < NN) {
            h_s[row][nt * 16 + lx] = f2b(y);
            if (l == NL - 1) onode[row * HD + nt * 16 + lx] = y;
          }
        }
      }
    }
    __syncthreads();
  }

  // ---- pooling ----
  if (t < HD) {
    float sm = 0.f, mx = -3.0e38f;
    for (int n = 0; n < NN; ++n) { float v = b2f(h_s[n][t]); sm += v; mx = fmaxf(mx, v); }
    pool_s[t] = sm * (1.0f / NN);
    pool_s[HD + t] = mx;
  }
  __syncthreads();

  // ---- output MLP (fp32) ----
  if (t < NOUT) {
    float a = b_out1[t];
    #pragma unroll 8
    for (int k = 0; k < 2 * HD; ++k) a += pool_s[k] * w_out1[k * NOUT + t];
    o1_s[t] = mish_f(a);
  }
  __syncthreads();
  if (t < NOUT) {
    float a = b_out2[t];
    #pragma unroll 8
    for (int k = 0; k < NOUT; ++k) a += o1_s[k] * w_out2[k * NOUT + t];
    out[(size_t)b * NOUT + t] = a;
  }
}

extern "C" void kernel_launch(void* const* d_in, const int* in_sizes, int n_in,
                              void* d_out, int out_size, void* d_ws, size_t ws_size,
                              hipStream_t stream) {
  const float* nf     = (const float*)d_in[0];
  const float* ef     = (const float*)d_in[1];
  const float* w_node = (const float*)d_in[2];
  const float* b_node = (const float*)d_in[3];
  const float* w_edge = (const float*)d_in[4];
  const float* b_edge = (const float*)d_in[5];
  const float* msg_w1 = (const float*)d_in[6];
  const float* msg_b1 = (const float*)d_in[7];
  const float* msg_w2 = (const float*)d_in[8];
  const float* msg_b2 = (const float*)d_in[9];
  const float* upd_w1 = (const float*)d_in[10];
  const float* upd_b1 = (const float*)d_in[11];
  const float* upd_w2 = (const float*)d_in[12];
  const float* upd_b2 = (const float*)d_in[13];
  const float* ln_g   = (const float*)d_in[14];
  const float* ln_b   = (const float*)d_in[15];
  const float* w_out1 = (const float*)d_in[16];
  const float* b_out1 = (const float*)d_in[17];
  const float* w_out2 = (const float*)d_in[18];
  const float* b_out2 = (const float*)d_in[19];
  const int* edge_index = (const int*)d_in[20];

  int*   wsi   = (int*)d_ws;                        // [0, 1024) bytes: CSR
  float* mb1   = (float*)d_ws + 256;                // [1024, 2048): folded msg bias
  short* frags = (short*)((char*)d_ws + 2048);      // [2048, 2048+102*1024): B-frags

  gnn_setup<<<32, 256, 0, stream>>>(w_node, w_edge, b_edge, msg_w1, msg_b1,
                                    msg_w2, upd_w1, upd_w2, edge_index,
                                    wsi, mb1, frags);
  gnn_main<<<NGR, 256, 0, stream>>>(nf, ef, b_node, msg_b2, upd_b1, upd_b2,
                                    ln_g, ln_b, w_out1, b_out1, w_out2, b_out2,
                                    edge_index, wsi, mb1, frags, (float*)d_out);
}